// Round 1
// baseline (9420.685 us; speedup 1.0000x reference)
//
#include <hip/hip_runtime.h>
#include <math.h>

#define NTOK 2048        // b*n = 2*1024
#define DIM_ 1024
#define NSEQ 1024
#define HEADS_ 16
#define HD 64
#define MLP_ 4096
#define EPS_ 1e-5f

// ---------------- LayerNorm: one block (256 thr) per row of 1024 ----------------
__global__ __launch_bounds__(256) void ln_kernel(const float* __restrict__ src,
                                                 float* __restrict__ dst,
                                                 const float* __restrict__ g,
                                                 const float* __restrict__ b) {
    int row = blockIdx.x;
    int t = threadIdx.x;
    const float4* x4 = (const float4*)(src + (size_t)row * DIM_);
    float4 f = x4[t];
    float s  = f.x + f.y + f.z + f.w;
    float sq = f.x*f.x + f.y*f.y + f.z*f.z + f.w*f.w;
    __shared__ float ssum[256], ssq[256];
    ssum[t] = s; ssq[t] = sq;
    __syncthreads();
    for (int o = 128; o > 0; o >>= 1) {
        if (t < o) { ssum[t] += ssum[t+o]; ssq[t] += ssq[t+o]; }
        __syncthreads();
    }
    float mu  = ssum[0] * (1.0f / DIM_);
    float var = ssq[0] * (1.0f / DIM_) - mu * mu;
    float r = rsqrtf(var + EPS_);
    const float4* g4 = (const float4*)g;
    const float4* b4 = (const float4*)b;
    float4 gg = g4[t], bb = b4[t];
    float4 o4;
    o4.x = (f.x - mu) * r * gg.x + bb.x;
    o4.y = (f.y - mu) * r * gg.y + bb.y;
    o4.z = (f.z - mu) * r * gg.z + bb.z;
    o4.w = (f.w - mu) * r * gg.w + bb.w;
    ((float4*)(dst + (size_t)row * DIM_))[t] = o4;
}

// ---------------- SGEMM: C[M,N] = A[M,K] @ B[K,N] (+bias)(+gelu)(+resid) ----------------
// 64x64 tile, BK=16, 256 threads, 4x4 acc per thread. All dims divide evenly.
#define BM 64
#define BN 64
#define BK 16
#define FLAG_BIAS  1
#define FLAG_GELU  2
#define FLAG_RESID 4

__global__ __launch_bounds__(256) void sgemm_kernel(const float* __restrict__ A,
                                                    const float* __restrict__ B,
                                                    float* __restrict__ C,
                                                    const float* __restrict__ bias,
                                                    const float* __restrict__ resid,
                                                    int M, int N, int K, int flags) {
    __shared__ float As[BK][BM + 1];   // +1 pad: store As[k][m], conflict-free
    __shared__ float Bs[BK][BN];
    int t = threadIdx.x;
    int tx = t & 15, ty = t >> 4;
    int row0 = blockIdx.y * BM;
    int col0 = blockIdx.x * BN;

    float acc[4][4];
    #pragma unroll
    for (int i = 0; i < 4; i++)
        #pragma unroll
        for (int j = 0; j < 4; j++) acc[i][j] = 0.0f;

    int ak = t & 15, ar = t >> 4;     // A load: k = t&15, row = (t>>4) + 16*it
    int bc = t & 63, bk = t >> 6;     // B load: col = t&63, k = (t>>6) + 4*it

    for (int k0 = 0; k0 < K; k0 += BK) {
        #pragma unroll
        for (int it = 0; it < 4; it++) {
            int r = ar + it * 16;
            As[ak][r] = A[(size_t)(row0 + r) * K + k0 + ak];
        }
        #pragma unroll
        for (int it = 0; it < 4; it++) {
            int k = bk + it * 4;
            Bs[k][bc] = B[(size_t)(k0 + k) * N + col0 + bc];
        }
        __syncthreads();
        #pragma unroll
        for (int k = 0; k < BK; k++) {
            float a0 = As[k][ty*4+0], a1 = As[k][ty*4+1], a2 = As[k][ty*4+2], a3 = As[k][ty*4+3];
            float b0 = Bs[k][tx*4+0], b1 = Bs[k][tx*4+1], b2 = Bs[k][tx*4+2], b3 = Bs[k][tx*4+3];
            acc[0][0] += a0*b0; acc[0][1] += a0*b1; acc[0][2] += a0*b2; acc[0][3] += a0*b3;
            acc[1][0] += a1*b0; acc[1][1] += a1*b1; acc[1][2] += a1*b2; acc[1][3] += a1*b3;
            acc[2][0] += a2*b0; acc[2][1] += a2*b1; acc[2][2] += a2*b2; acc[2][3] += a2*b3;
            acc[3][0] += a3*b0; acc[3][1] += a3*b1; acc[3][2] += a3*b2; acc[3][3] += a3*b3;
        }
        __syncthreads();
    }

    #pragma unroll
    for (int i = 0; i < 4; i++) {
        int row = row0 + ty*4 + i;
        #pragma unroll
        for (int j = 0; j < 4; j++) {
            int col = col0 + tx*4 + j;
            float v = acc[i][j];
            if (flags & FLAG_BIAS)  v += bias[col];
            if (flags & FLAG_GELU)  v = 0.5f * v * (1.0f + erff(v * 0.70710678118654752f));
            if (flags & FLAG_RESID) v += resid[(size_t)row * N + col];
            C[(size_t)row * N + col] = v;
        }
    }
}

// ---------------- Fused attention: one block (256 thr) per (b, h, query row) ----------------
// qkv layout: [b, n, 3, h, d] flat; out: [b, n, DIM]
__global__ __launch_bounds__(256) void attn_kernel(const float* __restrict__ qkv,
                                                   float* __restrict__ out) {
    int idx = blockIdx.x;
    int i = idx & (NSEQ - 1);
    int h = (idx >> 10) & (HEADS_ - 1);
    int b = idx >> 14;
    int t = threadIdx.x;

    __shared__ float q[HD];
    __shared__ float sc[NSEQ];
    __shared__ float red[256];
    __shared__ float part[4][HD];

    const float* qrow = qkv + ((size_t)(b * NSEQ + i)) * 3072 + h * HD;
    if (t < HD) q[t] = qrow[t];
    __syncthreads();

    const float scale = 0.03125f;  // DIM^-0.5 = 1/32 (full dim, per source)
    for (int j = t; j < NSEQ; j += 256) {
        const float* krow = qkv + ((size_t)(b * NSEQ + j)) * 3072 + 1024 + h * HD;
        float s = 0.0f;
        #pragma unroll
        for (int d = 0; d < HD; d++) s += q[d] * krow[d];
        sc[j] = s * scale;
    }
    __syncthreads();

    // max
    float m = -1e30f;
    for (int j = t; j < NSEQ; j += 256) m = fmaxf(m, sc[j]);
    red[t] = m;
    __syncthreads();
    for (int o = 128; o > 0; o >>= 1) {
        if (t < o) red[t] = fmaxf(red[t], red[t+o]);
        __syncthreads();
    }
    m = red[0];
    __syncthreads();

    // exp + sum
    float s = 0.0f;
    for (int j = t; j < NSEQ; j += 256) {
        float p = __expf(sc[j] - m);
        sc[j] = p;
        s += p;
    }
    red[t] = s;
    __syncthreads();
    for (int o = 128; o > 0; o >>= 1) {
        if (t < o) red[t] += red[t+o];
        __syncthreads();
    }
    float inv = 1.0f / red[0];
    __syncthreads();

    // out[d] = inv * sum_j p_j * V[j][d]; wave w covers j in [w*256, w*256+256)
    int lane = t & 63, w = t >> 6;
    float acc = 0.0f;
    for (int j = w * 256; j < w * 256 + 256; j++) {
        const float* vrow = qkv + ((size_t)(b * NSEQ + j)) * 3072 + 2048 + h * HD;
        acc += sc[j] * vrow[lane];
    }
    part[w][lane] = acc;
    __syncthreads();
    if (t < HD) {
        float o4 = (part[0][t] + part[1][t] + part[2][t] + part[3][t]) * inv;
        out[((size_t)(b * NSEQ + i)) * DIM_ + h * HD + t] = o4;
    }
}

extern "C" void kernel_launch(void* const* d_in, const int* in_sizes, int n_in,
                              void* d_out, int out_size, void* d_ws, size_t ws_size,
                              hipStream_t stream) {
    const float* x    = (const float*)d_in[0];
    const float* ln1g = (const float*)d_in[1];
    const float* ln1b = (const float*)d_in[2];
    const float* wqkv = (const float*)d_in[3];
    const float* wo   = (const float*)d_in[4];
    const float* bo   = (const float*)d_in[5];
    const float* ln2g = (const float*)d_in[6];
    const float* ln2b = (const float*)d_in[7];
    const float* w1   = (const float*)d_in[8];
    const float* b1   = (const float*)d_in[9];
    const float* w2   = (const float*)d_in[10];
    const float* b2   = (const float*)d_in[11];
    float* out = (float*)d_out;

    float* xcur = (float*)d_ws;                    // 2048*1024
    float* xn   = xcur + (size_t)NTOK * DIM_;      // 2048*1024
    float* qkv  = xn   + (size_t)NTOK * DIM_;      // 2048*3072
    float* aout = qkv  + (size_t)NTOK * 3 * DIM_;  // 2048*1024
    float* hdn  = aout + (size_t)NTOK * DIM_;      // 2048*4096

    hipMemcpyAsync(xcur, x, (size_t)NTOK * DIM_ * sizeof(float),
                   hipMemcpyDeviceToDevice, stream);

    for (int layer = 0; layer < 4; layer++) {
        // --- attention block ---
        ln_kernel<<<NTOK, 256, 0, stream>>>(xcur, xn, ln1g, ln1b);
        sgemm_kernel<<<dim3(3 * DIM_ / BN, NTOK / BM), 256, 0, stream>>>(
            xn, wqkv, qkv, nullptr, nullptr, NTOK, 3 * DIM_, DIM_, 0);
        attn_kernel<<<2 * HEADS_ * NSEQ, 256, 0, stream>>>(qkv, aout);
        sgemm_kernel<<<dim3(DIM_ / BN, NTOK / BM), 256, 0, stream>>>(
            aout, wo, xcur, bo, xcur, NTOK, DIM_, DIM_, FLAG_BIAS | FLAG_RESID);
        // --- MLP block ---
        ln_kernel<<<NTOK, 256, 0, stream>>>(xcur, xn, ln2g, ln2b);
        sgemm_kernel<<<dim3(MLP_ / BN, NTOK / BM), 256, 0, stream>>>(
            xn, w1, hdn, b1, nullptr, NTOK, MLP_, DIM_, FLAG_BIAS | FLAG_GELU);
        sgemm_kernel<<<dim3(DIM_ / BN, NTOK / BM), 256, 0, stream>>>(
            hdn, w2, xcur, b2, xcur, NTOK, DIM_, MLP_, FLAG_BIAS | FLAG_RESID);
    }

    hipMemcpyAsync(out, xcur, (size_t)NTOK * DIM_ * sizeof(float),
                   hipMemcpyDeviceToDevice, stream);
}

// Round 2
// 4429.853 us; speedup vs baseline: 2.1266x; 2.1266x over previous
//
#include <hip/hip_runtime.h>
#include <math.h>

#define NTOK 2048        // b*n = 2*1024
#define DIM_ 1024
#define NSEQ 1024
#define HEADS_ 16
#define HD 64
#define MLP_ 4096
#define EPS_ 1e-5f

// ---------------- LayerNorm: one block (256 thr) per row of 1024 ----------------
__global__ __launch_bounds__(256) void ln_kernel(const float* __restrict__ src,
                                                 float* __restrict__ dst,
                                                 const float* __restrict__ g,
                                                 const float* __restrict__ b) {
    int row = blockIdx.x;
    int t = threadIdx.x;
    const float4* x4 = (const float4*)(src + (size_t)row * DIM_);
    float4 f = x4[t];
    float s  = f.x + f.y + f.z + f.w;
    float sq = f.x*f.x + f.y*f.y + f.z*f.z + f.w*f.w;
    __shared__ float ssum[256], ssq[256];
    ssum[t] = s; ssq[t] = sq;
    __syncthreads();
    for (int o = 128; o > 0; o >>= 1) {
        if (t < o) { ssum[t] += ssum[t+o]; ssq[t] += ssq[t+o]; }
        __syncthreads();
    }
    float mu  = ssum[0] * (1.0f / DIM_);
    float var = ssq[0] * (1.0f / DIM_) - mu * mu;
    float r = rsqrtf(var + EPS_);
    const float4* g4 = (const float4*)g;
    const float4* b4 = (const float4*)b;
    float4 gg = g4[t], bb = b4[t];
    float4 o4;
    o4.x = (f.x - mu) * r * gg.x + bb.x;
    o4.y = (f.y - mu) * r * gg.y + bb.y;
    o4.z = (f.z - mu) * r * gg.z + bb.z;
    o4.w = (f.w - mu) * r * gg.w + bb.w;
    ((float4*)(dst + (size_t)row * DIM_))[t] = o4;
}

// ---------------- SGEMM: C[M,N] = A[M,K] @ B[K,N] (+bias)(+gelu)(+resid) ----------------
#define BM 64
#define BN 64
#define BK 16
#define FLAG_BIAS  1
#define FLAG_GELU  2
#define FLAG_RESID 4

__global__ __launch_bounds__(256) void sgemm_kernel(const float* __restrict__ A,
                                                    const float* __restrict__ B,
                                                    float* __restrict__ C,
                                                    const float* __restrict__ bias,
                                                    const float* __restrict__ resid,
                                                    int M, int N, int K, int flags) {
    __shared__ float As[BK][BM + 1];
    __shared__ float Bs[BK][BN];
    int t = threadIdx.x;
    int tx = t & 15, ty = t >> 4;
    int row0 = blockIdx.y * BM;
    int col0 = blockIdx.x * BN;

    float acc[4][4];
    #pragma unroll
    for (int i = 0; i < 4; i++)
        #pragma unroll
        for (int j = 0; j < 4; j++) acc[i][j] = 0.0f;

    int ak = t & 15, ar = t >> 4;
    int bc = t & 63, bk = t >> 6;

    for (int k0 = 0; k0 < K; k0 += BK) {
        #pragma unroll
        for (int it = 0; it < 4; it++) {
            int r = ar + it * 16;
            As[ak][r] = A[(size_t)(row0 + r) * K + k0 + ak];
        }
        #pragma unroll
        for (int it = 0; it < 4; it++) {
            int k = bk + it * 4;
            Bs[k][bc] = B[(size_t)(k0 + k) * N + col0 + bc];
        }
        __syncthreads();
        #pragma unroll
        for (int k = 0; k < BK; k++) {
            float a0 = As[k][ty*4+0], a1 = As[k][ty*4+1], a2 = As[k][ty*4+2], a3 = As[k][ty*4+3];
            float b0 = Bs[k][tx*4+0], b1 = Bs[k][tx*4+1], b2 = Bs[k][tx*4+2], b3 = Bs[k][tx*4+3];
            acc[0][0] += a0*b0; acc[0][1] += a0*b1; acc[0][2] += a0*b2; acc[0][3] += a0*b3;
            acc[1][0] += a1*b0; acc[1][1] += a1*b1; acc[1][2] += a1*b2; acc[1][3] += a1*b3;
            acc[2][0] += a2*b0; acc[2][1] += a2*b1; acc[2][2] += a2*b2; acc[2][3] += a2*b3;
            acc[3][0] += a3*b0; acc[3][1] += a3*b1; acc[3][2] += a3*b2; acc[3][3] += a3*b3;
        }
        __syncthreads();
    }

    #pragma unroll
    for (int i = 0; i < 4; i++) {
        int row = row0 + ty*4 + i;
        #pragma unroll
        for (int j = 0; j < 4; j++) {
            int col = col0 + tx*4 + j;
            float v = acc[i][j];
            if (flags & FLAG_BIAS)  v += bias[col];
            if (flags & FLAG_GELU)  v = 0.5f * v * (1.0f + erff(v * 0.70710678118654752f));
            if (flags & FLAG_RESID) v += resid[(size_t)row * N + col];
            C[(size_t)row * N + col] = v;
        }
    }
}

// ---------------- Flash attention: one block per (b, h, 64-query tile) ----------------
// qkv layout: [b, n, 3, h, d] flat; out: [b, n, DIM]
// 256 threads; thread (ty,tx) owns S/O rows ty*4+ii (queries) and cols tx*4+jj.
// Online softmax: rows of S live on 16 consecutive lanes (tx) -> shfl_xor(1,2,4,8).
__global__ __launch_bounds__(256) void fattn_kernel(const float* __restrict__ qkv,
                                                    float* __restrict__ out) {
    int idx = blockIdx.x;
    int qt = idx & 15;
    int h  = (idx >> 4) & 15;
    int b  = idx >> 8;
    int t  = threadIdx.x;
    int tx = t & 15, ty = t >> 4;

    // padded to 68 so all hot accesses are aligned ds_read_b128, <=2-way banks
    __shared__ float Qs[64][68];  // [d][i]  (transposed)
    __shared__ float Ks[64][68];  // [d][j]  (transposed)
    __shared__ float Vs[64][68];  // [j][d]
    __shared__ float Ps[64][68];  // [i][j]

    const size_t base = (size_t)b * NSEQ * 3072;
    const int i0 = qt * 64;
    const int d4 = tx * 4;

    // load Q tile (coalesced float4), store transposed
    #pragma unroll
    for (int pass = 0; pass < 4; pass++) {
        int i = ty + pass * 16;
        const float* qrow = qkv + base + (size_t)(i0 + i) * 3072 + h * HD;
        float4 f = *(const float4*)(qrow + d4);
        Qs[d4+0][i] = f.x; Qs[d4+1][i] = f.y; Qs[d4+2][i] = f.z; Qs[d4+3][i] = f.w;
    }

    float m_i[4], l_i[4], O[4][4];
    #pragma unroll
    for (int ii = 0; ii < 4; ii++) {
        m_i[ii] = -1e30f; l_i[ii] = 0.0f;
        #pragma unroll
        for (int dd = 0; dd < 4; dd++) O[ii][dd] = 0.0f;
    }

    const float scale = 0.03125f;  // DIM^-0.5 (full dim, per source)

    for (int j0 = 0; j0 < NSEQ; j0 += 64) {
        // stage K (transposed) and V (natural) tiles
        #pragma unroll
        for (int pass = 0; pass < 4; pass++) {
            int j = ty + pass * 16;
            const float* krow = qkv + base + (size_t)(j0 + j) * 3072 + 1024 + h * HD;
            float4 f = *(const float4*)(krow + d4);
            Ks[d4+0][j] = f.x; Ks[d4+1][j] = f.y; Ks[d4+2][j] = f.z; Ks[d4+3][j] = f.w;
            const float* vrow = qkv + base + (size_t)(j0 + j) * 3072 + 2048 + h * HD;
            *(float4*)&Vs[j][d4] = *(const float4*)(vrow + d4);
        }
        __syncthreads();   // covers Qs on first iteration too

        // S tile = Q @ K^T  (4x4 per thread)
        float acc[4][4];
        #pragma unroll
        for (int ii = 0; ii < 4; ii++)
            #pragma unroll
            for (int jj = 0; jj < 4; jj++) acc[ii][jj] = 0.0f;

        #pragma unroll 8
        for (int d = 0; d < 64; d++) {
            float4 a  = *(const float4*)&Qs[d][ty*4];
            float4 kv = *(const float4*)&Ks[d][tx*4];
            float av[4] = {a.x, a.y, a.z, a.w};
            float bv[4] = {kv.x, kv.y, kv.z, kv.w};
            #pragma unroll
            for (int ii = 0; ii < 4; ii++)
                #pragma unroll
                for (int jj = 0; jj < 4; jj++)
                    acc[ii][jj] += av[ii] * bv[jj];
        }

        // online softmax per query row (reduce across 16 tx lanes)
        #pragma unroll
        for (int ii = 0; ii < 4; ii++) {
            #pragma unroll
            for (int jj = 0; jj < 4; jj++) acc[ii][jj] *= scale;
            float rm = fmaxf(fmaxf(acc[ii][0], acc[ii][1]), fmaxf(acc[ii][2], acc[ii][3]));
            rm = fmaxf(rm, __shfl_xor(rm, 1));
            rm = fmaxf(rm, __shfl_xor(rm, 2));
            rm = fmaxf(rm, __shfl_xor(rm, 4));
            rm = fmaxf(rm, __shfl_xor(rm, 8));
            float newm = fmaxf(m_i[ii], rm);
            float alpha = __expf(m_i[ii] - newm);
            float rs = 0.0f;
            #pragma unroll
            for (int jj = 0; jj < 4; jj++) {
                float p = __expf(acc[ii][jj] - newm);
                acc[ii][jj] = p;
                rs += p;
            }
            rs += __shfl_xor(rs, 1);
            rs += __shfl_xor(rs, 2);
            rs += __shfl_xor(rs, 4);
            rs += __shfl_xor(rs, 8);
            l_i[ii] = l_i[ii] * alpha + rs;
            m_i[ii] = newm;
            #pragma unroll
            for (int dd = 0; dd < 4; dd++) O[ii][dd] *= alpha;
        }

        // P -> LDS [i][j] (float4 stores)
        #pragma unroll
        for (int ii = 0; ii < 4; ii++) {
            float4 p4 = make_float4(acc[ii][0], acc[ii][1], acc[ii][2], acc[ii][3]);
            *(float4*)&Ps[ty*4+ii][tx*4] = p4;
        }
        __syncthreads();

        // O += P @ V  (loop keys j, 4 at a time)
        #pragma unroll 4
        for (int j4 = 0; j4 < 64; j4 += 4) {
            float4 P0 = *(const float4*)&Ps[ty*4+0][j4];
            float4 P1 = *(const float4*)&Ps[ty*4+1][j4];
            float4 P2 = *(const float4*)&Ps[ty*4+2][j4];
            float4 P3 = *(const float4*)&Ps[ty*4+3][j4];
            float4 V0 = *(const float4*)&Vs[j4+0][tx*4];
            float4 V1 = *(const float4*)&Vs[j4+1][tx*4];
            float4 V2 = *(const float4*)&Vs[j4+2][tx*4];
            float4 V3 = *(const float4*)&Vs[j4+3][tx*4];
            float Pv[4][4] = {{P0.x,P0.y,P0.z,P0.w},{P1.x,P1.y,P1.z,P1.w},
                              {P2.x,P2.y,P2.z,P2.w},{P3.x,P3.y,P3.z,P3.w}};
            float Vv[4][4] = {{V0.x,V0.y,V0.z,V0.w},{V1.x,V1.y,V1.z,V1.w},
                              {V2.x,V2.y,V2.z,V2.w},{V3.x,V3.y,V3.z,V3.w}};
            #pragma unroll
            for (int ii = 0; ii < 4; ii++)
                #pragma unroll
                for (int dd = 0; dd < 4; dd++)
                    O[ii][dd] += Pv[ii][0]*Vv[0][dd] + Pv[ii][1]*Vv[1][dd]
                               + Pv[ii][2]*Vv[2][dd] + Pv[ii][3]*Vv[3][dd];
        }
        __syncthreads();   // protect Ks/Vs/Ps before next tile
    }

    #pragma unroll
    for (int ii = 0; ii < 4; ii++) {
        float inv = 1.0f / l_i[ii];
        float4 o4 = make_float4(O[ii][0]*inv, O[ii][1]*inv, O[ii][2]*inv, O[ii][3]*inv);
        *(float4*)(out + ((size_t)(b * NSEQ + i0 + ty*4 + ii)) * DIM_ + h * HD + tx*4) = o4;
    }
}

extern "C" void kernel_launch(void* const* d_in, const int* in_sizes, int n_in,
                              void* d_out, int out_size, void* d_ws, size_t ws_size,
                              hipStream_t stream) {
    const float* x    = (const float*)d_in[0];
    const float* ln1g = (const float*)d_in[1];
    const float* ln1b = (const float*)d_in[2];
    const float* wqkv = (const float*)d_in[3];
    const float* wo   = (const float*)d_in[4];
    const float* bo   = (const float*)d_in[5];
    const float* ln2g = (const float*)d_in[6];
    const float* ln2b = (const float*)d_in[7];
    const float* w1   = (const float*)d_in[8];
    const float* b1   = (const float*)d_in[9];
    const float* w2   = (const float*)d_in[10];
    const float* b2   = (const float*)d_in[11];
    float* out = (float*)d_out;

    float* xcur = (float*)d_ws;
    float* xn   = xcur + (size_t)NTOK * DIM_;
    float* qkv  = xn   + (size_t)NTOK * DIM_;
    float* aout = qkv  + (size_t)NTOK * 3 * DIM_;
    float* hdn  = aout + (size_t)NTOK * DIM_;

    hipMemcpyAsync(xcur, x, (size_t)NTOK * DIM_ * sizeof(float),
                   hipMemcpyDeviceToDevice, stream);

    for (int layer = 0; layer < 4; layer++) {
        ln_kernel<<<NTOK, 256, 0, stream>>>(xcur, xn, ln1g, ln1b);
        sgemm_kernel<<<dim3(3 * DIM_ / BN, NTOK / BM), 256, 0, stream>>>(
            xn, wqkv, qkv, nullptr, nullptr, NTOK, 3 * DIM_, DIM_, 0);
        fattn_kernel<<<2 * HEADS_ * (NSEQ / 64), 256, 0, stream>>>(qkv, aout);
        sgemm_kernel<<<dim3(DIM_ / BN, NTOK / BM), 256, 0, stream>>>(
            aout, wo, xcur, bo, xcur, NTOK, DIM_, DIM_, FLAG_BIAS | FLAG_RESID);
        ln_kernel<<<NTOK, 256, 0, stream>>>(xcur, xn, ln2g, ln2b);
        sgemm_kernel<<<dim3(MLP_ / BN, NTOK / BM), 256, 0, stream>>>(
            xn, w1, hdn, b1, nullptr, NTOK, MLP_, DIM_, FLAG_BIAS | FLAG_GELU);
        sgemm_kernel<<<dim3(DIM_ / BN, NTOK / BM), 256, 0, stream>>>(
            hdn, w2, xcur, b2, xcur, NTOK, DIM_, MLP_, FLAG_BIAS | FLAG_RESID);
    }

    hipMemcpyAsync(out, xcur, (size_t)NTOK * DIM_ * sizeof(float),
                   hipMemcpyDeviceToDevice, stream);
}

// Round 3
// 1836.796 us; speedup vs baseline: 5.1289x; 2.4117x over previous
//
#include <hip/hip_runtime.h>
#include <math.h>

#define NTOK 2048        // b*n
#define DIM_ 1024
#define NSEQ 1024
#define HEADS_ 16
#define HD 64
#define MLP_ 4096
#define EPS_ 1e-5f

#define FLAG_BIAS  1
#define FLAG_GELU  2
#define FLAG_RESID 4

typedef __attribute__((ext_vector_type(8))) short bf16x8;
typedef __attribute__((ext_vector_type(4))) float f32x4;

__device__ __forceinline__ unsigned short f2bf(float f) {   // RNE f32->bf16
    unsigned u = __float_as_uint(f);
    u += 0x7fffu + ((u >> 16) & 1u);
    return (unsigned short)(u >> 16);
}
__device__ __forceinline__ float bf2f(unsigned short u) {
    return __uint_as_float(((unsigned)u) << 16);
}
__device__ __forceinline__ void gld16(const unsigned short* g, short* l) {
    __builtin_amdgcn_global_load_lds(
        (const __attribute__((address_space(1))) void*)g,
        (__attribute__((address_space(3))) void*)l, 16, 0, 0);
}

// ---------------- weight convert: W[K][N] f32 -> Wt[N][K] bf16 ----------------
__global__ __launch_bounds__(256) void wconv_kernel(const float* __restrict__ W,
                                                    unsigned short* __restrict__ Wt,
                                                    int K, int N) {
    __shared__ float s[32][33];
    int n0 = blockIdx.x * 32, k0 = blockIdx.y * 32;
    int tx = threadIdx.x, ty = threadIdx.y;   // (32,8)
    #pragma unroll
    for (int r = 0; r < 4; r++) {
        int k = ty + r * 8;
        s[k][tx] = W[(size_t)(k0 + k) * N + n0 + tx];
    }
    __syncthreads();
    #pragma unroll
    for (int r = 0; r < 4; r++) {
        int n = ty + r * 8;
        Wt[(size_t)(n0 + n) * K + k0 + tx] = f2bf(s[tx][n]);
    }
}

// ---------------- LayerNorm: fp32 in -> bf16 out ----------------
__global__ __launch_bounds__(256) void ln_kernel(const float* __restrict__ src,
                                                 unsigned short* __restrict__ dst,
                                                 const float* __restrict__ g,
                                                 const float* __restrict__ b) {
    int row = blockIdx.x;
    int t = threadIdx.x;
    const float4* x4 = (const float4*)(src + (size_t)row * DIM_);
    float4 f = x4[t];
    float s  = f.x + f.y + f.z + f.w;
    float sq = f.x*f.x + f.y*f.y + f.z*f.z + f.w*f.w;
    __shared__ float ssum[256], ssq[256];
    ssum[t] = s; ssq[t] = sq;
    __syncthreads();
    for (int o = 128; o > 0; o >>= 1) {
        if (t < o) { ssum[t] += ssum[t+o]; ssq[t] += ssq[t+o]; }
        __syncthreads();
    }
    float mu  = ssum[0] * (1.0f / DIM_);
    float var = ssq[0] * (1.0f / DIM_) - mu * mu;
    float r = rsqrtf(var + EPS_);
    const float4* g4 = (const float4*)g;
    const float4* b4 = (const float4*)b;
    float4 gg = g4[t], bb = b4[t];
    ushort4 o4;
    o4.x = f2bf((f.x - mu) * r * gg.x + bb.x);
    o4.y = f2bf((f.y - mu) * r * gg.y + bb.y);
    o4.z = f2bf((f.z - mu) * r * gg.z + bb.z);
    o4.w = f2bf((f.w - mu) * r * gg.w + bb.w);
    ((ushort4*)(dst + (size_t)row * DIM_))[t] = o4;
}

// ---------------- MFMA GEMM: C[M,N] = A[M,K] @ Bt[N,K]^T ----------------
// 128x128 tile, BK=32, 256 thr (4 waves, 2x2 wave grid), 4x4 MFMAs of 16x16x32.
__global__ __launch_bounds__(256) void gemm_bt_kernel(const unsigned short* __restrict__ A,
                                                      const unsigned short* __restrict__ Bt,
                                                      float* __restrict__ Cf,
                                                      unsigned short* __restrict__ Cb,
                                                      const float* __restrict__ bias,
                                                      const float* __restrict__ resid,
                                                      int M, int N, int K, int flags) {
    __shared__ short As[128 * 32];
    __shared__ short Bs[128 * 32];
    int t = threadIdx.x;
    int lane = t & 63, w = t >> 6;
    int wm = w & 1, wn = w >> 1;
    int row0 = blockIdx.y * 128, col0 = blockIdx.x * 128;

    f32x4 acc[4][4];
    #pragma unroll
    for (int mi = 0; mi < 4; mi++)
        #pragma unroll
        for (int ni = 0; ni < 4; ni++) acc[mi][ni] = (f32x4){0.f, 0.f, 0.f, 0.f};

    // staging: thread t covers 8 bf16 at LDS elem t*8 (row t/4, col (t&3)*8); +2048 = +64 rows
    const unsigned short* Ag  = A  + (size_t)(row0 + (t >> 2)) * K + (t & 3) * 8;
    const unsigned short* Ag2 = Ag + (size_t)64 * K;
    const unsigned short* Bg  = Bt + (size_t)(col0 + (t >> 2)) * K + (t & 3) * 8;
    const unsigned short* Bg2 = Bg + (size_t)64 * K;
    short* Al = As + t * 8;
    short* Bl = Bs + t * 8;

    int mrow = (wm * 64 + (lane & 15)) * 32 + (lane >> 4) * 8;
    int nrow = (wn * 64 + (lane & 15)) * 32 + (lane >> 4) * 8;

    for (int k0 = 0; k0 < K; k0 += 32) {
        gld16(Ag + k0,  Al);
        gld16(Ag2 + k0, Al + 2048);
        gld16(Bg + k0,  Bl);
        gld16(Bg2 + k0, Bl + 2048);
        __syncthreads();

        bf16x8 af[4], bfr[4];
        #pragma unroll
        for (int mi = 0; mi < 4; mi++) af[mi]  = *(const bf16x8*)&As[mrow + mi * 16 * 32];
        #pragma unroll
        for (int ni = 0; ni < 4; ni++) bfr[ni] = *(const bf16x8*)&Bs[nrow + ni * 16 * 32];
        #pragma unroll
        for (int mi = 0; mi < 4; mi++)
            #pragma unroll
            for (int ni = 0; ni < 4; ni++)
                acc[mi][ni] = __builtin_amdgcn_mfma_f32_16x16x32_bf16(af[mi], bfr[ni],
                                                                      acc[mi][ni], 0, 0, 0);
        __syncthreads();
    }

    // epilogue: C/D map col=lane&15, row=(lane>>4)*4+reg  [m89-verified]
    int n_lane = lane & 15, quad = lane >> 4;
    #pragma unroll
    for (int mi = 0; mi < 4; mi++) {
        #pragma unroll
        for (int ni = 0; ni < 4; ni++) {
            int col = col0 + wn * 64 + ni * 16 + n_lane;
            float bv = (flags & FLAG_BIAS) ? bias[col] : 0.0f;
            #pragma unroll
            for (int r = 0; r < 4; r++) {
                int row = row0 + wm * 64 + mi * 16 + quad * 4 + r;
                float v = acc[mi][ni][r] + bv;
                if (flags & FLAG_GELU)  v = 0.5f * v * (1.0f + erff(v * 0.70710678118654752f));
                if (flags & FLAG_RESID) v += resid[(size_t)row * N + col];
                if (Cf) Cf[(size_t)row * N + col] = v;
                if (Cb) Cb[(size_t)row * N + col] = f2bf(v);
            }
        }
    }
}

// ---------------- Flash attention (bf16 qkv in, bf16 out) ----------------
__global__ __launch_bounds__(256) void fattn_kernel(const unsigned short* __restrict__ qkv,
                                                    unsigned short* __restrict__ out) {
    int idx = blockIdx.x;
    int qt = idx & 15;
    int h  = (idx >> 4) & 15;
    int b  = idx >> 8;
    int t  = threadIdx.x;
    int tx = t & 15, ty = t >> 4;

    __shared__ float Qs[64][68];
    __shared__ float Ks[64][68];
    __shared__ float Vs[64][68];
    __shared__ float Ps[64][68];

    const size_t base = (size_t)b * NSEQ * 3072;
    const int i0 = qt * 64;
    const int d4 = tx * 4;

    #pragma unroll
    for (int pass = 0; pass < 4; pass++) {
        int i = ty + pass * 16;
        const unsigned short* qrow = qkv + base + (size_t)(i0 + i) * 3072 + h * HD;
        ushort4 u = *(const ushort4*)(qrow + d4);
        Qs[d4+0][i] = bf2f(u.x); Qs[d4+1][i] = bf2f(u.y);
        Qs[d4+2][i] = bf2f(u.z); Qs[d4+3][i] = bf2f(u.w);
    }

    float m_i[4], l_i[4], O[4][4];
    #pragma unroll
    for (int ii = 0; ii < 4; ii++) {
        m_i[ii] = -1e30f; l_i[ii] = 0.0f;
        #pragma unroll
        for (int dd = 0; dd < 4; dd++) O[ii][dd] = 0.0f;
    }

    const float scale = 0.03125f;

    for (int j0 = 0; j0 < NSEQ; j0 += 64) {
        #pragma unroll
        for (int pass = 0; pass < 4; pass++) {
            int j = ty + pass * 16;
            const unsigned short* krow = qkv + base + (size_t)(j0 + j) * 3072 + 1024 + h * HD;
            ushort4 u = *(const ushort4*)(krow + d4);
            Ks[d4+0][j] = bf2f(u.x); Ks[d4+1][j] = bf2f(u.y);
            Ks[d4+2][j] = bf2f(u.z); Ks[d4+3][j] = bf2f(u.w);
            const unsigned short* vrow = qkv + base + (size_t)(j0 + j) * 3072 + 2048 + h * HD;
            ushort4 uv = *(const ushort4*)(vrow + d4);
            Vs[j][d4+0] = bf2f(uv.x); Vs[j][d4+1] = bf2f(uv.y);
            Vs[j][d4+2] = bf2f(uv.z); Vs[j][d4+3] = bf2f(uv.w);
        }
        __syncthreads();

        float acc[4][4];
        #pragma unroll
        for (int ii = 0; ii < 4; ii++)
            #pragma unroll
            for (int jj = 0; jj < 4; jj++) acc[ii][jj] = 0.0f;

        #pragma unroll 8
        for (int d = 0; d < 64; d++) {
            float4 a  = *(const float4*)&Qs[d][ty*4];
            float4 kv = *(const float4*)&Ks[d][tx*4];
            float av[4] = {a.x, a.y, a.z, a.w};
            float bv[4] = {kv.x, kv.y, kv.z, kv.w};
            #pragma unroll
            for (int ii = 0; ii < 4; ii++)
                #pragma unroll
                for (int jj = 0; jj < 4; jj++)
                    acc[ii][jj] += av[ii] * bv[jj];
        }

        #pragma unroll
        for (int ii = 0; ii < 4; ii++) {
            #pragma unroll
            for (int jj = 0; jj < 4; jj++) acc[ii][jj] *= scale;
            float rm = fmaxf(fmaxf(acc[ii][0], acc[ii][1]), fmaxf(acc[ii][2], acc[ii][3]));
            rm = fmaxf(rm, __shfl_xor(rm, 1));
            rm = fmaxf(rm, __shfl_xor(rm, 2));
            rm = fmaxf(rm, __shfl_xor(rm, 4));
            rm = fmaxf(rm, __shfl_xor(rm, 8));
            float newm = fmaxf(m_i[ii], rm);
            float alpha = __expf(m_i[ii] - newm);
            float rs = 0.0f;
            #pragma unroll
            for (int jj = 0; jj < 4; jj++) {
                float p = __expf(acc[ii][jj] - newm);
                acc[ii][jj] = p;
                rs += p;
            }
            rs += __shfl_xor(rs, 1);
            rs += __shfl_xor(rs, 2);
            rs += __shfl_xor(rs, 4);
            rs += __shfl_xor(rs, 8);
            l_i[ii] = l_i[ii] * alpha + rs;
            m_i[ii] = newm;
            #pragma unroll
            for (int dd = 0; dd < 4; dd++) O[ii][dd] *= alpha;
        }

        #pragma unroll
        for (int ii = 0; ii < 4; ii++)
            *(float4*)&Ps[ty*4+ii][tx*4] = make_float4(acc[ii][0], acc[ii][1], acc[ii][2], acc[ii][3]);
        __syncthreads();

        #pragma unroll 4
        for (int j4 = 0; j4 < 64; j4 += 4) {
            float4 P0 = *(const float4*)&Ps[ty*4+0][j4];
            float4 P1 = *(const float4*)&Ps[ty*4+1][j4];
            float4 P2 = *(const float4*)&Ps[ty*4+2][j4];
            float4 P3 = *(const float4*)&Ps[ty*4+3][j4];
            float4 V0 = *(const float4*)&Vs[j4+0][tx*4];
            float4 V1 = *(const float4*)&Vs[j4+1][tx*4];
            float4 V2 = *(const float4*)&Vs[j4+2][tx*4];
            float4 V3 = *(const float4*)&Vs[j4+3][tx*4];
            float Pv[4][4] = {{P0.x,P0.y,P0.z,P0.w},{P1.x,P1.y,P1.z,P1.w},
                              {P2.x,P2.y,P2.z,P2.w},{P3.x,P3.y,P3.z,P3.w}};
            float Vv[4][4] = {{V0.x,V0.y,V0.z,V0.w},{V1.x,V1.y,V1.z,V1.w},
                              {V2.x,V2.y,V2.z,V2.w},{V3.x,V3.y,V3.z,V3.w}};
            #pragma unroll
            for (int ii = 0; ii < 4; ii++)
                #pragma unroll
                for (int dd = 0; dd < 4; dd++)
                    O[ii][dd] += Pv[ii][0]*Vv[0][dd] + Pv[ii][1]*Vv[1][dd]
                               + Pv[ii][2]*Vv[2][dd] + Pv[ii][3]*Vv[3][dd];
        }
        __syncthreads();
    }

    #pragma unroll
    for (int ii = 0; ii < 4; ii++) {
        float inv = 1.0f / l_i[ii];
        ushort4 o4;
        o4.x = f2bf(O[ii][0]*inv); o4.y = f2bf(O[ii][1]*inv);
        o4.z = f2bf(O[ii][2]*inv); o4.w = f2bf(O[ii][3]*inv);
        *(ushort4*)(out + ((size_t)(b * NSEQ + i0 + ty*4 + ii)) * DIM_ + h * HD + tx*4) = o4;
    }
}

extern "C" void kernel_launch(void* const* d_in, const int* in_sizes, int n_in,
                              void* d_out, int out_size, void* d_ws, size_t ws_size,
                              hipStream_t stream) {
    const float* x    = (const float*)d_in[0];
    const float* ln1g = (const float*)d_in[1];
    const float* ln1b = (const float*)d_in[2];
    const float* wqkv = (const float*)d_in[3];
    const float* wo   = (const float*)d_in[4];
    const float* bo   = (const float*)d_in[5];
    const float* ln2g = (const float*)d_in[6];
    const float* ln2b = (const float*)d_in[7];
    const float* w1   = (const float*)d_in[8];
    const float* b1   = (const float*)d_in[9];
    const float* w2   = (const float*)d_in[10];
    const float* b2   = (const float*)d_in[11];
    float* out = (float*)d_out;

    char* ws = (char*)d_ws;
    float*          xcur = (float*)(ws);                         // 8 MB
    unsigned short* qkv  = (unsigned short*)(ws + (8u<<20));     // 12 MB
    unsigned short* xn   = (unsigned short*)(ws + (20u<<20));    // 4 MB
    unsigned short* aout = (unsigned short*)(ws + (24u<<20));    // 4 MB
    unsigned short* hdn  = (unsigned short*)(ws + (28u<<20));    // 16 MB
    unsigned short* wtqkv= (unsigned short*)(ws + (44u<<20));    // 6 MB
    unsigned short* wto  = (unsigned short*)(ws + (50u<<20));    // 2 MB
    unsigned short* wt1  = (unsigned short*)(ws + (52u<<20));    // 8 MB
    unsigned short* wt2  = (unsigned short*)(ws + (60u<<20));    // 8 MB -> 68 MB total

    // per-launch weight transpose+convert (graph-safe: same work every call)
    wconv_kernel<<<dim3(3*DIM_/32, DIM_/32), dim3(32,8), 0, stream>>>(wqkv, wtqkv, DIM_, 3*DIM_);
    wconv_kernel<<<dim3(DIM_/32,   DIM_/32), dim3(32,8), 0, stream>>>(wo,   wto,   DIM_, DIM_);
    wconv_kernel<<<dim3(MLP_/32,   DIM_/32), dim3(32,8), 0, stream>>>(w1,   wt1,   DIM_, MLP_);
    wconv_kernel<<<dim3(DIM_/32,   MLP_/32), dim3(32,8), 0, stream>>>(w2,   wt2,   MLP_, DIM_);

    hipMemcpyAsync(xcur, x, (size_t)NTOK * DIM_ * sizeof(float),
                   hipMemcpyDeviceToDevice, stream);

    for (int layer = 0; layer < 4; layer++) {
        ln_kernel<<<NTOK, 256, 0, stream>>>(xcur, xn, ln1g, ln1b);
        gemm_bt_kernel<<<dim3(3*DIM_/128, NTOK/128), 256, 0, stream>>>(
            xn, wtqkv, nullptr, qkv, nullptr, nullptr, NTOK, 3*DIM_, DIM_, 0);
        fattn_kernel<<<2 * HEADS_ * (NSEQ / 64), 256, 0, stream>>>(qkv, aout);
        gemm_bt_kernel<<<dim3(DIM_/128, NTOK/128), 256, 0, stream>>>(
            aout, wto, xcur, nullptr, bo, xcur, NTOK, DIM_, DIM_, FLAG_BIAS | FLAG_RESID);
        ln_kernel<<<NTOK, 256, 0, stream>>>(xcur, xn, ln2g, ln2b);
        gemm_bt_kernel<<<dim3(MLP_/128, NTOK/128), 256, 0, stream>>>(
            xn, wt1, nullptr, hdn, b1, nullptr, NTOK, MLP_, DIM_, FLAG_BIAS | FLAG_GELU);
        gemm_bt_kernel<<<dim3(DIM_/128, NTOK/128), 256, 0, stream>>>(
            hdn, wt2, xcur, nullptr, b2, xcur, NTOK, DIM_, MLP_, FLAG_BIAS | FLAG_RESID);
    }

    hipMemcpyAsync(out, xcur, (size_t)NTOK * DIM_ * sizeof(float),
                   hipMemcpyDeviceToDevice, stream);
}

// Round 4
// 1228.456 us; speedup vs baseline: 7.6687x; 1.4952x over previous
//
#include <hip/hip_runtime.h>
#include <math.h>

#define NTOK 2048        // b*n
#define DIM_ 1024
#define NSEQ 1024
#define HEADS_ 16
#define HD 64
#define MLP_ 4096
#define EPS_ 1e-5f

#define FLAG_BIAS  1
#define FLAG_GELU  2
#define FLAG_RESID 4

typedef __attribute__((ext_vector_type(8))) short bf16x8;
typedef __attribute__((ext_vector_type(4))) float f32x4;

__device__ __forceinline__ unsigned short f2bf(float f) {   // RNE f32->bf16
    unsigned u = __float_as_uint(f);
    u += 0x7fffu + ((u >> 16) & 1u);
    return (unsigned short)(u >> 16);
}
__device__ __forceinline__ float bf2f(unsigned short u) {
    return __uint_as_float(((unsigned)u) << 16);
}
__device__ __forceinline__ void gld16(const unsigned short* g, short* l) {
    __builtin_amdgcn_global_load_lds(
        (const __attribute__((address_space(1))) void*)g,
        (__attribute__((address_space(3))) void*)l, 16, 0, 0);
}

// ---------------- weight convert: W[K][N] f32 -> Wt[N][K] bf16 ----------------
// cols < qcols get multiplied by qscale (used to fold the 2^-5 attention scale
// into the Q block of w_qkv — exact, power of two).
__global__ __launch_bounds__(256) void wconv_kernel(const float* __restrict__ W,
                                                    unsigned short* __restrict__ Wt,
                                                    int K, int N,
                                                    float qscale, int qcols) {
    __shared__ float s[32][33];
    int n0 = blockIdx.x * 32, k0 = blockIdx.y * 32;
    int tx = threadIdx.x, ty = threadIdx.y;   // (32,8)
    #pragma unroll
    for (int r = 0; r < 4; r++) {
        int k = ty + r * 8;
        s[k][tx] = W[(size_t)(k0 + k) * N + n0 + tx];
    }
    __syncthreads();
    #pragma unroll
    for (int r = 0; r < 4; r++) {
        int n = ty + r * 8;
        float v = s[tx][n];
        if (n0 + n < qcols) v *= qscale;
        Wt[(size_t)(n0 + n) * K + k0 + tx] = f2bf(v);
    }
}

// ---------------- LayerNorm: fp32 in -> bf16 out ----------------
__global__ __launch_bounds__(256) void ln_kernel(const float* __restrict__ src,
                                                 unsigned short* __restrict__ dst,
                                                 const float* __restrict__ g,
                                                 const float* __restrict__ b) {
    int row = blockIdx.x;
    int t = threadIdx.x;
    const float4* x4 = (const float4*)(src + (size_t)row * DIM_);
    float4 f = x4[t];
    float s  = f.x + f.y + f.z + f.w;
    float sq = f.x*f.x + f.y*f.y + f.z*f.z + f.w*f.w;
    __shared__ float ssum[256], ssq[256];
    ssum[t] = s; ssq[t] = sq;
    __syncthreads();
    for (int o = 128; o > 0; o >>= 1) {
        if (t < o) { ssum[t] += ssum[t+o]; ssq[t] += ssq[t+o]; }
        __syncthreads();
    }
    float mu  = ssum[0] * (1.0f / DIM_);
    float var = ssq[0] * (1.0f / DIM_) - mu * mu;
    float r = rsqrtf(var + EPS_);
    const float4* g4 = (const float4*)g;
    const float4* b4 = (const float4*)b;
    float4 gg = g4[t], bb = b4[t];
    ushort4 o4;
    o4.x = f2bf((f.x - mu) * r * gg.x + bb.x);
    o4.y = f2bf((f.y - mu) * r * gg.y + bb.y);
    o4.z = f2bf((f.z - mu) * r * gg.z + bb.z);
    o4.w = f2bf((f.w - mu) * r * gg.w + bb.w);
    ((ushort4*)(dst + (size_t)row * DIM_))[t] = o4;
}

// ---------------- MFMA GEMM: C[M,N] = A[M,K] @ Bt[N,K]^T ----------------
__global__ __launch_bounds__(256) void gemm_bt_kernel(const unsigned short* __restrict__ A,
                                                      const unsigned short* __restrict__ Bt,
                                                      float* __restrict__ Cf,
                                                      unsigned short* __restrict__ Cb,
                                                      const float* __restrict__ bias,
                                                      const float* __restrict__ resid,
                                                      int M, int N, int K, int flags) {
    __shared__ short As[128 * 32];
    __shared__ short Bs[128 * 32];
    int t = threadIdx.x;
    int lane = t & 63, w = t >> 6;
    int wm = w & 1, wn = w >> 1;
    int row0 = blockIdx.y * 128, col0 = blockIdx.x * 128;

    f32x4 acc[4][4];
    #pragma unroll
    for (int mi = 0; mi < 4; mi++)
        #pragma unroll
        for (int ni = 0; ni < 4; ni++) acc[mi][ni] = (f32x4){0.f, 0.f, 0.f, 0.f};

    const unsigned short* Ag  = A  + (size_t)(row0 + (t >> 2)) * K + (t & 3) * 8;
    const unsigned short* Ag2 = Ag + (size_t)64 * K;
    const unsigned short* Bg  = Bt + (size_t)(col0 + (t >> 2)) * K + (t & 3) * 8;
    const unsigned short* Bg2 = Bg + (size_t)64 * K;
    short* Al = As + t * 8;
    short* Bl = Bs + t * 8;

    int mrow = (wm * 64 + (lane & 15)) * 32 + (lane >> 4) * 8;
    int nrow = (wn * 64 + (lane & 15)) * 32 + (lane >> 4) * 8;

    for (int k0 = 0; k0 < K; k0 += 32) {
        gld16(Ag + k0,  Al);
        gld16(Ag2 + k0, Al + 2048);
        gld16(Bg + k0,  Bl);
        gld16(Bg2 + k0, Bl + 2048);
        __syncthreads();

        bf16x8 af[4], bfr[4];
        #pragma unroll
        for (int mi = 0; mi < 4; mi++) af[mi]  = *(const bf16x8*)&As[mrow + mi * 16 * 32];
        #pragma unroll
        for (int ni = 0; ni < 4; ni++) bfr[ni] = *(const bf16x8*)&Bs[nrow + ni * 16 * 32];
        #pragma unroll
        for (int mi = 0; mi < 4; mi++)
            #pragma unroll
            for (int ni = 0; ni < 4; ni++)
                acc[mi][ni] = __builtin_amdgcn_mfma_f32_16x16x32_bf16(af[mi], bfr[ni],
                                                                      acc[mi][ni], 0, 0, 0);
        __syncthreads();
    }

    int n_lane = lane & 15, quad = lane >> 4;
    #pragma unroll
    for (int mi = 0; mi < 4; mi++) {
        #pragma unroll
        for (int ni = 0; ni < 4; ni++) {
            int col = col0 + wn * 64 + ni * 16 + n_lane;
            float bv = (flags & FLAG_BIAS) ? bias[col] : 0.0f;
            #pragma unroll
            for (int r = 0; r < 4; r++) {
                int row = row0 + wm * 64 + mi * 16 + quad * 4 + r;
                float v = acc[mi][ni][r] + bv;
                if (flags & FLAG_GELU)  v = 0.5f * v * (1.0f + erff(v * 0.70710678118654752f));
                if (flags & FLAG_RESID) v += resid[(size_t)row * N + col];
                if (Cf) Cf[(size_t)row * N + col] = v;
                if (Cb) Cb[(size_t)row * N + col] = f2bf(v);
            }
        }
    }
}

// ---------------- V transpose: qkv[b,n,2048+h*64+d] -> Vt[b,h,d,n] ----------------
__global__ __launch_bounds__(256) void vt_kernel(const unsigned short* __restrict__ qkv,
                                                 unsigned short* __restrict__ VtG) {
    int idx = blockIdx.x;
    int nt = idx & 15;
    int h  = (idx >> 4) & 15;
    int b  = idx >> 8;
    int t = threadIdx.x;
    int lane = t & 63, w = t >> 6;
    __shared__ unsigned short S[64 * 72];
    const size_t base = (size_t)b * NSEQ * 3072 + 2048 + h * HD;
    int n0 = nt * 64;
    int srow = t >> 3, sc = (t & 7) * 8;
    #pragma unroll
    for (int pass = 0; pass < 2; pass++) {
        int n = srow + pass * 32;
        bf16x8 v = *(const bf16x8*)(qkv + base + (size_t)(n0 + n) * 3072 + sc);
        *(bf16x8*)&S[n * 72 + sc] = v;
    }
    __syncthreads();
    int d = lane;
    #pragma unroll
    for (int pass = 0; pass < 2; pass++) {
        int jc = w * 2 + pass;
        union { bf16x8 v; unsigned short u[8]; } o;
        #pragma unroll
        for (int k = 0; k < 8; k++) o.u[k] = S[(jc * 8 + k) * 72 + d];  // 2-way banks: free
        *(bf16x8*)(VtG + ((size_t)(b * 16 + h) * 64 + d) * 1024 + n0 + jc * 8) = o.v;
    }
}

// ---------------- MFMA flash attention ----------------
// block = (b, h, 64-query tile); 4 waves, wave w owns Q rows [w*16, w*16+16).
// Q scale is pre-folded into w_qkv. K used natural [j][d]; V via pre-transposed Vt [d][j].
__global__ __launch_bounds__(256) void fattn_kernel(const unsigned short* __restrict__ qkv,
                                                    const unsigned short* __restrict__ VtG,
                                                    unsigned short* __restrict__ out) {
    int idx = blockIdx.x;
    int qt = idx & 15;
    int h  = (idx >> 4) & 15;
    int b  = idx >> 8;
    int t  = threadIdx.x;
    int lane = t & 63, w = t >> 6;
    int m = lane & 15, quad = lane >> 4;

    __shared__ unsigned short Ks[64 * 72];       // [j][d], stride 72
    __shared__ unsigned short Vs[64 * 72];       // [d][j], stride 72
    __shared__ unsigned short Ps[4][16 * 72];    // per-wave P [i][j]

    const size_t base = (size_t)b * NSEQ * 3072;
    const int i0 = qt * 64;

    // Q fragments, registers for whole kernel: A[i=m][k=c*32+quad*8..]
    bf16x8 aq0, aq1;
    {
        const unsigned short* qrow = qkv + base + (size_t)(i0 + w * 16 + m) * 3072 + h * HD;
        aq0 = *(const bf16x8*)(qrow + quad * 8);
        aq1 = *(const bf16x8*)(qrow + 32 + quad * 8);
    }

    f32x4 Oacc[4];
    #pragma unroll
    for (int dt = 0; dt < 4; dt++) Oacc[dt] = (f32x4){0.f, 0.f, 0.f, 0.f};
    float m_i[4] = {-1e30f, -1e30f, -1e30f, -1e30f};
    float l_i[4] = {0.f, 0.f, 0.f, 0.f};

    int srow = t >> 3, sc = (t & 7) * 8;
    const unsigned short* Kg = qkv + base + 1024 + h * HD + (size_t)srow * 3072 + sc;
    const unsigned short* Vg = VtG + ((size_t)(b * 16 + h) * 64 + srow) * 1024 + sc;

    for (int j0 = 0; j0 < NSEQ; j0 += 64) {
        // stage K[64][64] and Vt[64][64] (each thread: 2 rows per tile)
        #pragma unroll
        for (int pass = 0; pass < 2; pass++) {
            int r = srow + pass * 32;
            bf16x8 kv = *(const bf16x8*)(Kg + (size_t)(j0 + pass * 32) * 3072);
            bf16x8 vv = *(const bf16x8*)(Vg + j0 + (size_t)pass * 32 * 1024);
            *(bf16x8*)&Ks[r * 72 + sc] = kv;
            *(bf16x8*)&Vs[r * 72 + sc] = vv;
        }
        __syncthreads();

        // S = Q @ K^T : rows quad*4+r, cols nt*16+m
        f32x4 s[4];
        #pragma unroll
        for (int nt = 0; nt < 4; nt++) {
            const unsigned short* kr = &Ks[(nt * 16 + m) * 72 + quad * 8];
            bf16x8 b0 = *(const bf16x8*)kr;
            bf16x8 b1 = *(const bf16x8*)(kr + 32);
            f32x4 a = (f32x4){0.f, 0.f, 0.f, 0.f};
            a = __builtin_amdgcn_mfma_f32_16x16x32_bf16(aq0, b0, a, 0, 0, 0);
            a = __builtin_amdgcn_mfma_f32_16x16x32_bf16(aq1, b1, a, 0, 0, 0);
            s[nt] = a;
        }

        // online softmax (rows live on 16-lane groups; quad preserved by xor<16)
        float alpha[4];
        #pragma unroll
        for (int r = 0; r < 4; r++) {
            float v0 = s[0][r], v1 = s[1][r], v2 = s[2][r], v3 = s[3][r];
            float rm = fmaxf(fmaxf(v0, v1), fmaxf(v2, v3));
            rm = fmaxf(rm, __shfl_xor(rm, 1));
            rm = fmaxf(rm, __shfl_xor(rm, 2));
            rm = fmaxf(rm, __shfl_xor(rm, 4));
            rm = fmaxf(rm, __shfl_xor(rm, 8));
            float newm = fmaxf(m_i[r], rm);
            float al = __expf(m_i[r] - newm);
            float p0 = __expf(v0 - newm);
            float p1 = __expf(v1 - newm);
            float p2 = __expf(v2 - newm);
            float p3 = __expf(v3 - newm);
            float rs = p0 + p1 + p2 + p3;
            rs += __shfl_xor(rs, 1);
            rs += __shfl_xor(rs, 2);
            rs += __shfl_xor(rs, 4);
            rs += __shfl_xor(rs, 8);
            l_i[r] = l_i[r] * al + rs;
            m_i[r] = newm;
            alpha[r] = al;
            unsigned short* pr = &Ps[w][(quad * 4 + r) * 72 + m];
            pr[0]  = f2bf(p0);
            pr[16] = f2bf(p1);
            pr[32] = f2bf(p2);
            pr[48] = f2bf(p3);
        }
        #pragma unroll
        for (int dt = 0; dt < 4; dt++) {
            Oacc[dt][0] *= alpha[0];
            Oacc[dt][1] *= alpha[1];
            Oacc[dt][2] *= alpha[2];
            Oacc[dt][3] *= alpha[3];
        }

        // O += P @ V : A = Ps[w][i=m][k=j], B = Vs[d][j]  (same-wave P, no barrier)
        const unsigned short* pa = &Ps[w][m * 72 + quad * 8];
        bf16x8 ap0 = *(const bf16x8*)pa;
        bf16x8 ap1 = *(const bf16x8*)(pa + 32);
        #pragma unroll
        for (int dt = 0; dt < 4; dt++) {
            const unsigned short* vr = &Vs[(dt * 16 + m) * 72 + quad * 8];
            bf16x8 b0 = *(const bf16x8*)vr;
            bf16x8 b1 = *(const bf16x8*)(vr + 32);
            Oacc[dt] = __builtin_amdgcn_mfma_f32_16x16x32_bf16(ap0, b0, Oacc[dt], 0, 0, 0);
            Oacc[dt] = __builtin_amdgcn_mfma_f32_16x16x32_bf16(ap1, b1, Oacc[dt], 0, 0, 0);
        }
        __syncthreads();
    }

    #pragma unroll
    for (int r = 0; r < 4; r++) {
        float inv = 1.0f / l_i[r];
        int row = i0 + w * 16 + quad * 4 + r;
        unsigned short* orow = out + ((size_t)(b * NSEQ + row)) * DIM_ + h * HD + m;
        orow[0]  = f2bf(Oacc[0][r] * inv);
        orow[16] = f2bf(Oacc[1][r] * inv);
        orow[32] = f2bf(Oacc[2][r] * inv);
        orow[48] = f2bf(Oacc[3][r] * inv);
    }
}

extern "C" void kernel_launch(void* const* d_in, const int* in_sizes, int n_in,
                              void* d_out, int out_size, void* d_ws, size_t ws_size,
                              hipStream_t stream) {
    const float* x    = (const float*)d_in[0];
    const float* ln1g = (const float*)d_in[1];
    const float* ln1b = (const float*)d_in[2];
    const float* wqkv = (const float*)d_in[3];
    const float* wo   = (const float*)d_in[4];
    const float* bo   = (const float*)d_in[5];
    const float* ln2g = (const float*)d_in[6];
    const float* ln2b = (const float*)d_in[7];
    const float* w1   = (const float*)d_in[8];
    const float* b1   = (const float*)d_in[9];
    const float* w2   = (const float*)d_in[10];
    const float* b2   = (const float*)d_in[11];
    float* out = (float*)d_out;

    char* ws = (char*)d_ws;
    float*          xcur = (float*)(ws);                         // 8 MB
    unsigned short* qkv  = (unsigned short*)(ws + (8u<<20));     // 12 MB
    unsigned short* xn   = (unsigned short*)(ws + (20u<<20));    // 4 MB
    unsigned short* aout = (unsigned short*)(ws + (24u<<20));    // 4 MB
    unsigned short* hdn  = (unsigned short*)(ws + (28u<<20));    // 16 MB
    unsigned short* wtqkv= (unsigned short*)(ws + (44u<<20));    // 6 MB
    unsigned short* wto  = (unsigned short*)(ws + (50u<<20));    // 2 MB
    unsigned short* wt1  = (unsigned short*)(ws + (52u<<20));    // 8 MB
    unsigned short* wt2  = (unsigned short*)(ws + (60u<<20));    // 8 MB
    unsigned short* VtG  = (unsigned short*)(ws + (68u<<20));    // 4 MB -> 72 MB total

    wconv_kernel<<<dim3(3*DIM_/32, DIM_/32), dim3(32,8), 0, stream>>>(wqkv, wtqkv, DIM_, 3*DIM_,
                                                                      0.03125f, DIM_);
    wconv_kernel<<<dim3(DIM_/32,   DIM_/32), dim3(32,8), 0, stream>>>(wo,   wto, DIM_, DIM_, 1.f, 0);
    wconv_kernel<<<dim3(MLP_/32,   DIM_/32), dim3(32,8), 0, stream>>>(w1,   wt1, DIM_, MLP_, 1.f, 0);
    wconv_kernel<<<dim3(DIM_/32,   MLP_/32), dim3(32,8), 0, stream>>>(w2,   wt2, MLP_, DIM_, 1.f, 0);

    hipMemcpyAsync(xcur, x, (size_t)NTOK * DIM_ * sizeof(float),
                   hipMemcpyDeviceToDevice, stream);

    for (int layer = 0; layer < 4; layer++) {
        ln_kernel<<<NTOK, 256, 0, stream>>>(xcur, xn, ln1g, ln1b);
        gemm_bt_kernel<<<dim3(3*DIM_/128, NTOK/128), 256, 0, stream>>>(
            xn, wtqkv, nullptr, qkv, nullptr, nullptr, NTOK, 3*DIM_, DIM_, 0);
        vt_kernel<<<512, 256, 0, stream>>>(qkv, VtG);
        fattn_kernel<<<512, 256, 0, stream>>>(qkv, VtG, aout);
        gemm_bt_kernel<<<dim3(DIM_/128, NTOK/128), 256, 0, stream>>>(
            aout, wto, xcur, nullptr, bo, xcur, NTOK, DIM_, DIM_, FLAG_BIAS | FLAG_RESID);
        ln_kernel<<<NTOK, 256, 0, stream>>>(xcur, xn, ln2g, ln2b);
        gemm_bt_kernel<<<dim3(MLP_/128, NTOK/128), 256, 0, stream>>>(
            xn, wt1, nullptr, hdn, b1, nullptr, NTOK, MLP_, DIM_, FLAG_BIAS | FLAG_GELU);
        gemm_bt_kernel<<<dim3(DIM_/128, NTOK/128), 256, 0, stream>>>(
            hdn, wt2, xcur, nullptr, b2, xcur, NTOK, DIM_, MLP_, FLAG_BIAS | FLAG_RESID);
    }

    hipMemcpyAsync(out, xcur, (size_t)NTOK * DIM_ * sizeof(float),
                   hipMemcpyDeviceToDevice, stream);
}

// Round 5
// 940.673 us; speedup vs baseline: 10.0148x; 1.3059x over previous
//
#include <hip/hip_runtime.h>
#include <math.h>

#define NTOK 2048        // b*n
#define DIM_ 1024
#define NSEQ 1024
#define HEADS_ 16
#define HD 64
#define MLP_ 4096
#define EPS_ 1e-5f

#define FLAG_BIAS  1
#define FLAG_GELU  2
#define FLAG_RESID 4
#define FLAG_QKV   8
#define FLAG_PART  16

typedef __attribute__((ext_vector_type(8))) short bf16x8;
typedef __attribute__((ext_vector_type(4))) float f32x4;

__device__ __forceinline__ unsigned short f2bf(float f) {   // RNE f32->bf16
    unsigned u = __float_as_uint(f);
    u += 0x7fffu + ((u >> 16) & 1u);
    return (unsigned short)(u >> 16);
}
__device__ __forceinline__ float bf2f(unsigned short u) {
    return __uint_as_float(((unsigned)u) << 16);
}
__device__ __forceinline__ void gld16(const unsigned short* g, short* l) {
    __builtin_amdgcn_global_load_lds(
        (const __attribute__((address_space(1))) void*)g,
        (__attribute__((address_space(3))) void*)l, 16, 0, 0);
}

// ---------------- weight convert: W[K][N] f32 -> Wt[N][K] bf16 ----------------
__global__ __launch_bounds__(256) void wconv_kernel(const float* __restrict__ W,
                                                    unsigned short* __restrict__ Wt,
                                                    int K, int N,
                                                    float qscale, int qcols) {
    __shared__ float s[32][33];
    int n0 = blockIdx.x * 32, k0 = blockIdx.y * 32;
    int tx = threadIdx.x, ty = threadIdx.y;   // (32,8)
    #pragma unroll
    for (int r = 0; r < 4; r++) {
        int k = ty + r * 8;
        s[k][tx] = W[(size_t)(k0 + k) * N + n0 + tx];
    }
    __syncthreads();
    #pragma unroll
    for (int r = 0; r < 4; r++) {
        int n = ty + r * 8;
        float v = s[tx][n];
        if (n0 + n < qcols) v *= qscale;
        Wt[(size_t)(n0 + n) * K + k0 + tx] = f2bf(v);
    }
}

// ---------------- LayerNorm: fp32 in -> bf16 out ----------------
__global__ __launch_bounds__(256) void ln_kernel(const float* __restrict__ src,
                                                 unsigned short* __restrict__ dst,
                                                 const float* __restrict__ g,
                                                 const float* __restrict__ b) {
    int row = blockIdx.x;
    int t = threadIdx.x;
    const float4* x4 = (const float4*)(src + (size_t)row * DIM_);
    float4 f = x4[t];
    float s  = f.x + f.y + f.z + f.w;
    float sq = f.x*f.x + f.y*f.y + f.z*f.z + f.w*f.w;
    __shared__ float ssum[256], ssq[256];
    ssum[t] = s; ssq[t] = sq;
    __syncthreads();
    for (int o = 128; o > 0; o >>= 1) {
        if (t < o) { ssum[t] += ssum[t+o]; ssq[t] += ssq[t+o]; }
        __syncthreads();
    }
    float mu  = ssum[0] * (1.0f / DIM_);
    float var = ssq[0] * (1.0f / DIM_) - mu * mu;
    float r = rsqrtf(var + EPS_);
    const float4* g4 = (const float4*)g;
    const float4* b4 = (const float4*)b;
    float4 gg = g4[t], bb = b4[t];
    ushort4 o4;
    o4.x = f2bf((f.x - mu) * r * gg.x + bb.x);
    o4.y = f2bf((f.y - mu) * r * gg.y + bb.y);
    o4.z = f2bf((f.z - mu) * r * gg.z + bb.z);
    o4.w = f2bf((f.w - mu) * r * gg.w + bb.w);
    ((ushort4*)(dst + (size_t)row * DIM_))[t] = o4;
}

// ---------------- single-wave MFMA GEMM: 64x64 tile, BK=32 ----------------
// C[M,N] = A[M,K] @ Bt[N,K]^T over K-chunk [z*KC, (z+1)*KC).
// FLAG_PART: write fp32 partial to Cpart + z*M*N (no epilogue).
// FLAG_QKV:  cols < 2048 -> Cb (ldcb=2048); cols >= 2048 (V) -> Vt[b,h,d,n] transposed.
__global__ __launch_bounds__(64) void gemm64_kernel(const unsigned short* __restrict__ A,
                                                    const unsigned short* __restrict__ Bt,
                                                    unsigned short* __restrict__ Cb,
                                                    unsigned short* __restrict__ Vt,
                                                    float* __restrict__ Cpart,
                                                    const float* __restrict__ bias,
                                                    int M, int N, int K, int KC,
                                                    int ldcb, int flags) {
    __shared__ __align__(16) short As[64 * 32];
    __shared__ __align__(16) short Bs[64 * 32];
    int t = threadIdx.x;
    int m = t & 15, quad = t >> 4;
    int col0 = blockIdx.x * 64, row0 = blockIdx.y * 64;
    int z = blockIdx.z;
    int k_beg = z * KC, k_end = k_beg + KC;

    f32x4 acc[4][4];
    #pragma unroll
    for (int mi = 0; mi < 4; mi++)
        #pragma unroll
        for (int ni = 0; ni < 4; ni++) acc[mi][ni] = (f32x4){0.f, 0.f, 0.f, 0.f};

    const unsigned short* Ag = A  + (size_t)(row0 + (t >> 2)) * K + (t & 3) * 8;
    const unsigned short* Bg = Bt + (size_t)(col0 + (t >> 2)) * K + (t & 3) * 8;
    short* Al = As + t * 8;
    short* Bl = Bs + t * 8;

    for (int k0 = k_beg; k0 < k_end; k0 += 32) {
        #pragma unroll
        for (int p = 0; p < 4; p++) {
            gld16(Ag + (size_t)p * 16 * K + k0, Al + p * 512);
            gld16(Bg + (size_t)p * 16 * K + k0, Bl + p * 512);
        }
        __syncthreads();
        bf16x8 af[4], bfr[4];
        #pragma unroll
        for (int mi = 0; mi < 4; mi++) af[mi]  = *(const bf16x8*)&As[(mi * 16 + m) * 32 + quad * 8];
        #pragma unroll
        for (int ni = 0; ni < 4; ni++) bfr[ni] = *(const bf16x8*)&Bs[(ni * 16 + m) * 32 + quad * 8];
        #pragma unroll
        for (int mi = 0; mi < 4; mi++)
            #pragma unroll
            for (int ni = 0; ni < 4; ni++)
                acc[mi][ni] = __builtin_amdgcn_mfma_f32_16x16x32_bf16(af[mi], bfr[ni],
                                                                      acc[mi][ni], 0, 0, 0);
        __syncthreads();
    }

    if (flags & FLAG_PART) {
        float* P = Cpart + (size_t)z * M * N;
        #pragma unroll
        for (int mi = 0; mi < 4; mi++)
            #pragma unroll
            for (int ni = 0; ni < 4; ni++) {
                int col = col0 + ni * 16 + m;
                #pragma unroll
                for (int r = 0; r < 4; r++) {
                    int row = row0 + mi * 16 + quad * 4 + r;
                    P[(size_t)row * N + col] = acc[mi][ni][r];
                }
            }
        return;
    }

    if ((flags & FLAG_QKV) && col0 >= 2048) {   // V region -> transposed Vt[b,h,d,n]
        int h = (col0 - 2048) >> 6;
        #pragma unroll
        for (int mi = 0; mi < 4; mi++) {
            int tok0 = row0 + mi * 16 + quad * 4;        // 4 consecutive tokens, same b
            int bb = tok0 >> 10, nn = tok0 & 1023;
            #pragma unroll
            for (int ni = 0; ni < 4; ni++) {
                int d = ni * 16 + m;
                ushort4 o4;
                o4.x = f2bf(acc[mi][ni][0]);
                o4.y = f2bf(acc[mi][ni][1]);
                o4.z = f2bf(acc[mi][ni][2]);
                o4.w = f2bf(acc[mi][ni][3]);
                *(ushort4*)(Vt + ((size_t)(bb * 16 + h) * 64 + d) * 1024 + nn) = o4;
            }
        }
        return;
    }

    #pragma unroll
    for (int mi = 0; mi < 4; mi++)
        #pragma unroll
        for (int ni = 0; ni < 4; ni++) {
            int col = col0 + ni * 16 + m;
            float bv = (flags & FLAG_BIAS) ? bias[col] : 0.0f;
            #pragma unroll
            for (int r = 0; r < 4; r++) {
                int row = row0 + mi * 16 + quad * 4 + r;
                float v = acc[mi][ni][r] + bv;
                if (flags & FLAG_GELU) v = 0.5f * v * (1.0f + erff(v * 0.70710678118654752f));
                Cb[(size_t)row * ldcb + col] = f2bf(v);
            }
        }
}

// ---------------- split-K reduce: out = p0 + p1 + bias + resid (fp32) ----------------
__global__ __launch_bounds__(256) void reduce2_kernel(const float* __restrict__ P,
                                                      const float* __restrict__ bias,
                                                      const float* __restrict__ resid,
                                                      float* __restrict__ outF,
                                                      int MN, int N) {
    int i = (blockIdx.x * 256 + threadIdx.x) * 4;
    float4 a  = *(const float4*)(P + i);
    float4 b  = *(const float4*)(P + MN + i);
    float4 bi = *(const float4*)(bias + (i & (N - 1)));
    float4 rs = *(const float4*)(resid + i);
    float4 o;
    o.x = a.x + b.x + bi.x + rs.x;
    o.y = a.y + b.y + bi.y + rs.y;
    o.z = a.z + b.z + bi.z + rs.z;
    o.w = a.w + b.w + bi.w + rs.w;
    *(float4*)(outF + i) = o;
}

// ---------------- MFMA flash attention ----------------
// qk layout: [b, n, 2048] (Q at h*64, K at 1024+h*64); V via pre-transposed Vt[b,h,d,n].
__global__ __launch_bounds__(256) void fattn_kernel(const unsigned short* __restrict__ qk,
                                                    const unsigned short* __restrict__ VtG,
                                                    unsigned short* __restrict__ out) {
    int idx = blockIdx.x;
    int qt = idx & 15;
    int h  = (idx >> 4) & 15;
    int b  = idx >> 8;
    int t  = threadIdx.x;
    int lane = t & 63, w = t >> 6;
    int m = lane & 15, quad = lane >> 4;

    __shared__ unsigned short Ks[64 * 72];       // [j][d], stride 72
    __shared__ unsigned short Vs[64 * 72];       // [d][j], stride 72
    __shared__ unsigned short Ps[4][16 * 72];    // per-wave P [i][j]

    const size_t base = (size_t)b * NSEQ * 2048;
    const int i0 = qt * 64;

    bf16x8 aq0, aq1;
    {
        const unsigned short* qrow = qk + base + (size_t)(i0 + w * 16 + m) * 2048 + h * HD;
        aq0 = *(const bf16x8*)(qrow + quad * 8);
        aq1 = *(const bf16x8*)(qrow + 32 + quad * 8);
    }

    f32x4 Oacc[4];
    #pragma unroll
    for (int dt = 0; dt < 4; dt++) Oacc[dt] = (f32x4){0.f, 0.f, 0.f, 0.f};
    float m_i[4] = {-1e30f, -1e30f, -1e30f, -1e30f};
    float l_i[4] = {0.f, 0.f, 0.f, 0.f};

    int srow = t >> 3, sc = (t & 7) * 8;
    const unsigned short* Kg = qk + base + 1024 + h * HD + (size_t)srow * 2048 + sc;
    const unsigned short* Vg = VtG + ((size_t)(b * 16 + h) * 64 + srow) * 1024 + sc;

    for (int j0 = 0; j0 < NSEQ; j0 += 64) {
        #pragma unroll
        for (int pass = 0; pass < 2; pass++) {
            int r = srow + pass * 32;
            bf16x8 kv = *(const bf16x8*)(Kg + (size_t)(j0 + pass * 32) * 2048);
            bf16x8 vv = *(const bf16x8*)(Vg + j0 + (size_t)pass * 32 * 1024);
            *(bf16x8*)&Ks[r * 72 + sc] = kv;
            *(bf16x8*)&Vs[r * 72 + sc] = vv;
        }
        __syncthreads();

        f32x4 s[4];
        #pragma unroll
        for (int nt = 0; nt < 4; nt++) {
            const unsigned short* kr = &Ks[(nt * 16 + m) * 72 + quad * 8];
            bf16x8 b0 = *(const bf16x8*)kr;
            bf16x8 b1 = *(const bf16x8*)(kr + 32);
            f32x4 a = (f32x4){0.f, 0.f, 0.f, 0.f};
            a = __builtin_amdgcn_mfma_f32_16x16x32_bf16(aq0, b0, a, 0, 0, 0);
            a = __builtin_amdgcn_mfma_f32_16x16x32_bf16(aq1, b1, a, 0, 0, 0);
            s[nt] = a;
        }

        float alpha[4];
        #pragma unroll
        for (int r = 0; r < 4; r++) {
            float v0 = s[0][r], v1 = s[1][r], v2 = s[2][r], v3 = s[3][r];
            float rm = fmaxf(fmaxf(v0, v1), fmaxf(v2, v3));
            rm = fmaxf(rm, __shfl_xor(rm, 1));
            rm = fmaxf(rm, __shfl_xor(rm, 2));
            rm = fmaxf(rm, __shfl_xor(rm, 4));
            rm = fmaxf(rm, __shfl_xor(rm, 8));
            float newm = fmaxf(m_i[r], rm);
            float al = __expf(m_i[r] - newm);
            float p0 = __expf(v0 - newm);
            float p1 = __expf(v1 - newm);
            float p2 = __expf(v2 - newm);
            float p3 = __expf(v3 - newm);
            float rs = p0 + p1 + p2 + p3;
            rs += __shfl_xor(rs, 1);
            rs += __shfl_xor(rs, 2);
            rs += __shfl_xor(rs, 4);
            rs += __shfl_xor(rs, 8);
            l_i[r] = l_i[r] * al + rs;
            m_i[r] = newm;
            alpha[r] = al;
            unsigned short* pr = &Ps[w][(quad * 4 + r) * 72 + m];
            pr[0]  = f2bf(p0);
            pr[16] = f2bf(p1);
            pr[32] = f2bf(p2);
            pr[48] = f2bf(p3);
        }
        #pragma unroll
        for (int dt = 0; dt < 4; dt++) {
            Oacc[dt][0] *= alpha[0];
            Oacc[dt][1] *= alpha[1];
            Oacc[dt][2] *= alpha[2];
            Oacc[dt][3] *= alpha[3];
        }

        const unsigned short* pa = &Ps[w][m * 72 + quad * 8];
        bf16x8 ap0 = *(const bf16x8*)pa;
        bf16x8 ap1 = *(const bf16x8*)(pa + 32);
        #pragma unroll
        for (int dt = 0; dt < 4; dt++) {
            const unsigned short* vr = &Vs[(dt * 16 + m) * 72 + quad * 8];
            bf16x8 b0 = *(const bf16x8*)vr;
            bf16x8 b1 = *(const bf16x8*)(vr + 32);
            Oacc[dt] = __builtin_amdgcn_mfma_f32_16x16x32_bf16(ap0, b0, Oacc[dt], 0, 0, 0);
            Oacc[dt] = __builtin_amdgcn_mfma_f32_16x16x32_bf16(ap1, b1, Oacc[dt], 0, 0, 0);
        }
        __syncthreads();
    }

    #pragma unroll
    for (int r = 0; r < 4; r++) {
        float inv = 1.0f / l_i[r];
        int row = i0 + w * 16 + quad * 4 + r;
        unsigned short* orow = out + ((size_t)(b * NSEQ + row)) * DIM_ + h * HD + m;
        orow[0]  = f2bf(Oacc[0][r] * inv);
        orow[16] = f2bf(Oacc[1][r] * inv);
        orow[32] = f2bf(Oacc[2][r] * inv);
        orow[48] = f2bf(Oacc[3][r] * inv);
    }
}

extern "C" void kernel_launch(void* const* d_in, const int* in_sizes, int n_in,
                              void* d_out, int out_size, void* d_ws, size_t ws_size,
                              hipStream_t stream) {
    const float* x    = (const float*)d_in[0];
    const float* ln1g = (const float*)d_in[1];
    const float* ln1b = (const float*)d_in[2];
    const float* wqkv = (const float*)d_in[3];
    const float* wo   = (const float*)d_in[4];
    const float* bo   = (const float*)d_in[5];
    const float* ln2g = (const float*)d_in[6];
    const float* ln2b = (const float*)d_in[7];
    const float* w1   = (const float*)d_in[8];
    const float* b1   = (const float*)d_in[9];
    const float* w2   = (const float*)d_in[10];
    const float* b2   = (const float*)d_in[11];
    float* out = (float*)d_out;

    // layout (MB): xcur 0-8 | qk 8-16 | xn 16-20 | aout 20-24 | hdn 24-40 |
    //              wtqkv 40-46 | wto 46-48 | wt1 48-56 | wt2 56-64 | VtG 64-68
    // overlays: mlp2 partials @8-24 (qk+xn+aout dead), o partials @24-40 (hdn dead)
    char* ws = (char*)d_ws;
    float*          xcur = (float*)(ws);
    unsigned short* qk   = (unsigned short*)(ws + (8u<<20));
    unsigned short* xn   = (unsigned short*)(ws + (16u<<20));
    unsigned short* aout = (unsigned short*)(ws + (20u<<20));
    unsigned short* hdn  = (unsigned short*)(ws + (24u<<20));
    unsigned short* wtqkv= (unsigned short*)(ws + (40u<<20));
    unsigned short* wto  = (unsigned short*)(ws + (46u<<20));
    unsigned short* wt1  = (unsigned short*)(ws + (48u<<20));
    unsigned short* wt2  = (unsigned short*)(ws + (56u<<20));
    unsigned short* VtG  = (unsigned short*)(ws + (64u<<20));
    float* m2part = (float*)(ws + (8u<<20));
    float* opart  = (float*)(ws + (24u<<20));

    wconv_kernel<<<dim3(3*DIM_/32, DIM_/32), dim3(32,8), 0, stream>>>(wqkv, wtqkv, DIM_, 3*DIM_,
                                                                      0.03125f, DIM_);
    wconv_kernel<<<dim3(DIM_/32,   DIM_/32), dim3(32,8), 0, stream>>>(wo,   wto, DIM_, DIM_, 1.f, 0);
    wconv_kernel<<<dim3(MLP_/32,   DIM_/32), dim3(32,8), 0, stream>>>(w1,   wt1, DIM_, MLP_, 1.f, 0);
    wconv_kernel<<<dim3(DIM_/32,   MLP_/32), dim3(32,8), 0, stream>>>(w2,   wt2, MLP_, DIM_, 1.f, 0);

    hipMemcpyAsync(xcur, x, (size_t)NTOK * DIM_ * sizeof(float),
                   hipMemcpyDeviceToDevice, stream);

    for (int layer = 0; layer < 4; layer++) {
        ln_kernel<<<NTOK, 256, 0, stream>>>(xcur, xn, ln1g, ln1b);
        // qkv: Q,K -> qk (stride 2048); V -> VtG transposed
        gemm64_kernel<<<dim3(3*DIM_/64, NTOK/64, 1), 64, 0, stream>>>(
            xn, wtqkv, qk, VtG, nullptr, nullptr,
            NTOK, 3*DIM_, DIM_, DIM_, 2048, FLAG_QKV);
        fattn_kernel<<<512, 256, 0, stream>>>(qk, VtG, aout);
        // o-proj: split-K 2 -> partials in hdn region
        gemm64_kernel<<<dim3(DIM_/64, NTOK/64, 2), 64, 0, stream>>>(
            aout, wto, nullptr, nullptr, opart, nullptr,
            NTOK, DIM_, DIM_, DIM_/2, 0, FLAG_PART);
        reduce2_kernel<<<NTOK*DIM_/1024, 256, 0, stream>>>(opart, bo, xcur, xcur,
                                                           NTOK*DIM_, DIM_);
        ln_kernel<<<NTOK, 256, 0, stream>>>(xcur, xn, ln2g, ln2b);
        gemm64_kernel<<<dim3(MLP_/64, NTOK/64, 1), 64, 0, stream>>>(
            xn, wt1, hdn, nullptr, nullptr, b1,
            NTOK, MLP_, DIM_, DIM_, MLP_, FLAG_BIAS | FLAG_GELU);
        // mlp2: split-K 2 -> partials in qk+xn+aout region
        gemm64_kernel<<<dim3(DIM_/64, NTOK/64, 2), 64, 0, stream>>>(
            hdn, wt2, nullptr, nullptr, m2part, nullptr,
            NTOK, DIM_, MLP_, MLP_/2, 0, FLAG_PART);
        reduce2_kernel<<<NTOK*DIM_/1024, 256, 0, stream>>>(m2part, b2, xcur, xcur,
                                                           NTOK*DIM_, DIM_);
    }

    hipMemcpyAsync(out, xcur, (size_t)NTOK * DIM_ * sizeof(float),
                   hipMemcpyDeviceToDevice, stream);
}